// Round 1
// baseline (1959.844 us; speedup 1.0000x reference)
//
#include <hip/hip_runtime.h>
#include <hip/hip_bf16.h>

#define SEQ   2048
#define BATCH 512
#define ISZ   64
#define HSZ   128

// One block per batch row. 256 threads: thread t -> h = t>>1, half = t&1.
// Each thread holds Wh[h][half*64 .. +64] and Wi[h][half*32 .. +32] in VGPRs.
// Per step: 96 FMAs, pair-combine via shfl_xor(1), tanh, h exchanged via LDS.
// x staged in LDS in 32-step double-buffered chunks, prefetched ~16 steps ahead.
__launch_bounds__(256, 2)
__global__ void rnn_fused(const float* __restrict__ x,
                          const float* __restrict__ Wh,
                          const float* __restrict__ bh,
                          const float* __restrict__ Wi,
                          const float* __restrict__ bi,
                          float* __restrict__ out)
{
    __shared__ __align__(16) float xbuf[2][32][ISZ];   // 16 KB
    __shared__ __align__(16) float hbuf[2][HSZ];       // 1 KB

    const int tid  = threadIdx.x;
    const int b    = blockIdx.x;
    const int h    = tid >> 1;
    const int half = tid & 1;

    // ---- weights into registers (one-time; Wh/Wi are L2/L3-resident) ----
    float whr[64];
    {
        const float4* wp = (const float4*)(Wh + h * HSZ + half * 64);
        #pragma unroll
        for (int j = 0; j < 16; ++j) {
            float4 v = wp[j];
            whr[4*j+0] = v.x; whr[4*j+1] = v.y; whr[4*j+2] = v.z; whr[4*j+3] = v.w;
        }
    }
    float wir[32];
    {
        const float4* wp = (const float4*)(Wi + h * ISZ + half * 32);
        #pragma unroll
        for (int j = 0; j < 8; ++j) {
            float4 v = wp[j];
            wir[4*j+0] = v.x; wir[4*j+1] = v.y; wir[4*j+2] = v.z; wir[4*j+3] = v.w;
        }
    }
    const float bias = bh[h] + bi[h];

    // ---- init h0 = 0 and preload x chunk 0 ----
    if (tid < HSZ) hbuf[0][tid] = 0.f;
    const int s  = tid >> 4;   // 0..15
    const int i4 = tid & 15;   // 0..15  (float4 column)
    {
        float4 c0 = *(const float4*)(x + ((0  + s) * BATCH + b) * ISZ + i4 * 4);
        float4 c1 = *(const float4*)(x + ((16 + s) * BATCH + b) * ISZ + i4 * 4);
        *(float4*)&xbuf[0][s][i4 * 4]      = c0;
        *(float4*)&xbuf[0][16 + s][i4 * 4] = c1;
    }
    __syncthreads();

    float4 p0 = make_float4(0.f, 0.f, 0.f, 0.f);
    float4 p1 = p0;
    float  hn = 0.f;

    #pragma unroll 2
    for (int t = 0; t < SEQ; ++t) {
        const int cb  = (t >> 5) & 1;   // current x chunk buffer
        const int cur = t & 1;          // hbuf read buffer
        const int nxt = cur ^ 1;

        // prefetch next x chunk: issue loads at step%32==0, commit to LDS at ==16
        if ((t & 31) == 0 && t + 32 < SEQ) {
            p0 = *(const float4*)(x + ((t + 32 + s) * BATCH + b) * ISZ + i4 * 4);
            p1 = *(const float4*)(x + ((t + 48 + s) * BATCH + b) * ISZ + i4 * 4);
        }
        if ((t & 31) == 16 && t + 16 < SEQ) {
            *(float4*)&xbuf[cb ^ 1][s][i4 * 4]      = p0;
            *(float4*)&xbuf[cb ^ 1][16 + s][i4 * 4] = p1;
        }

        // ---- half-dot: 64 Wh terms + 32 Wi terms ----
        float a0 = 0.f, a1 = 0.f, a2 = 0.f, a3 = 0.f;
        const float4* hb = (const float4*)(&hbuf[cur][half * 64]);
        #pragma unroll
        for (int j = 0; j < 16; ++j) {
            float4 hv = hb[j];
            a0 += whr[4*j+0] * hv.x; a1 += whr[4*j+1] * hv.y;
            a2 += whr[4*j+2] * hv.z; a3 += whr[4*j+3] * hv.w;
        }
        const float4* xb = (const float4*)(&xbuf[cb][t & 31][half * 32]);
        #pragma unroll
        for (int j = 0; j < 8; ++j) {
            float4 xv = xb[j];
            a0 += wir[4*j+0] * xv.x; a1 += wir[4*j+1] * xv.y;
            a2 += wir[4*j+2] * xv.z; a3 += wir[4*j+3] * xv.w;
        }
        float acc = (a0 + a1) + (a2 + a3);
        acc += __shfl_xor(acc, 1, 64);   // combine the two K-halves (intra-wave pair)
        acc += bias;

        // tanh(x) = 1 - 2/(exp(2x)+1); saturates correctly at +/-inf
        float e = __expf(2.f * acc);
        hn = 1.f - 2.f * __builtin_amdgcn_rcpf(e + 1.f);

        if (half == 0) {
            hbuf[nxt][h] = hn;
            out[(size_t)(t * BATCH + b) * HSZ + h] = hn;
        }

        // barrier WITHOUT vmcnt drain: only LDS ops must be visible; keep the
        // x prefetch global loads and h_seq stores in flight across steps.
        asm volatile("s_waitcnt lgkmcnt(0)\n\ts_barrier" ::: "memory");
    }

    // final hidden state
    if (half == 0) {
        out[(size_t)SEQ * BATCH * HSZ + b * HSZ + h] = hn;
    }
}

extern "C" void kernel_launch(void* const* d_in, const int* in_sizes, int n_in,
                              void* d_out, int out_size, void* d_ws, size_t ws_size,
                              hipStream_t stream)
{
    const float* x  = (const float*)d_in[0];
    const float* Wh = (const float*)d_in[1];
    const float* bh = (const float*)d_in[2];
    const float* Wi = (const float*)d_in[3];
    const float* bi = (const float*)d_in[4];
    float* out = (float*)d_out;

    dim3 grid(BATCH);
    dim3 block(256);
    hipLaunchKernelGGL(rnn_fused, grid, block, 0, stream, x, Wh, bh, Wi, bi, out);
}